// Round 2
// baseline (2303.180 us; speedup 1.0000x reference)
//
#include <hip/hip_runtime.h>
#include <math.h>

#define V 30000
#define E 200
#define T 100
#define N 2048
#define NITER 100
#define NB 240
#define JPB 125          // columns (words) per block: 240*125 = 30000
#define SL 101           // LDS row stride (pad 100->101: conflict-free both passes)
#define EPS_OT 1e-16f
#define EPS_LOG 1e-12f

// workspace float offsets
#define OFF_KTW   0            // T*V  [t][j]
#define OFF_KDT   3000000      // N*T  [n][t]
#define OFF_WW    3204800      // V
#define OFF_DD    3234800      // N
#define OFF_TT    3236848      // 128
#define OFF_PM    3236976      // 128  per-block softmax max partials
#define OFF_PS    3237104      // 128  per-block softmax sum partials
#define OFF_ACCTW 3237232      // NITER*T
#define OFF_ACCDT 3247232      // NITER*T
#define OFF_VTW   3257232      // V
#define OFF_UDT   3287232      // N
#define OFF_UTW   3289280      // 128
#define OFF_VDT   3289408      // 128
#define OFF_DBL   3289536      // 8 doubles: [0]=dsr(slow) [1]=loss_dt [2]=loss_tw [3]=bow_total
#define OFF_CNT   3289552      // 128 ints (iteration barrier counters)
#define OFF_FLAG  3289680      // 1 int (theta nonzero)

// ---------- norms + zeroing + word-softmax partials ----------
__global__ void k_pre(const float* __restrict__ we, const float* __restrict__ de,
                      const float* __restrict__ te, const float* __restrict__ wwgt,
                      float* ws) {
    __shared__ float red[256];
    int tid = threadIdx.x, b = blockIdx.x;
    int gid = b * 256 + tid;
    if (gid < 2 * NITER * T) ws[OFF_ACCTW + gid] = 0.f;
    if (gid < 152) ws[OFF_DBL + gid] = 0.f;   // dbl(16) + cnt(128) + flag(8)
    {   // squared row norms
        int r = gid;
        const float* src = nullptr; float* dst = nullptr; int row = 0;
        if (r < V)              { src = we; dst = ws + OFF_WW; row = r; }
        else if (r < V + N)     { src = de; dst = ws + OFF_DD; row = r - V; }
        else if (r < V + N + T) { src = te; dst = ws + OFF_TT; row = r - V - N; }
        if (src) {
            const float4* p = (const float4*)(src + (size_t)row * E);
            float s = 0.f;
            #pragma unroll 10
            for (int i = 0; i < E / 4; i++) { float4 v = p[i]; s += v.x*v.x + v.y*v.y + v.z*v.z + v.w*v.w; }
            dst[row] = s;
        }
    }
    if (b < 118) {  // word-weights softmax partials (combined later per-block in k_persist)
        int j = gid;
        float w = (j < V) ? wwgt[j] : -INFINITY;
        red[tid] = w; __syncthreads();
        for (int s = 128; s > 0; s >>= 1) { if (tid < s) red[tid] = fmaxf(red[tid], red[tid + s]); __syncthreads(); }
        float m = red[0]; __syncthreads();
        float e = (j < V) ? expf(w - m) : 0.f;
        red[tid] = e; __syncthreads();
        for (int s = 128; s > 0; s >>= 1) { if (tid < s) red[tid] += red[tid + s]; __syncthreads(); }
        if (tid == 0) { ws[OFF_PM + b] = m; ws[OFF_PS + b] = red[0]; }
    }
}

// ---------- K_TW[t][j] = exp(-2*sqdist) ----------
__global__ void k_ktw(const float* __restrict__ we, const float* __restrict__ te, float* ws) {
    __shared__ float wt[8][256];
    __shared__ float tp[8][25];
    __shared__ float tts[25];
    int tid = threadIdx.x;
    int j0 = blockIdx.x * 256;
    int t0 = blockIdx.y * 25;
    int j = j0 + tid;
    int jl = (j < V) ? j : V - 1;
    float acc[25];
    #pragma unroll
    for (int i = 0; i < 25; i++) acc[i] = 0.f;
    if (tid < 25) tts[tid] = ws[OFF_TT + t0 + tid];
    for (int kk = 0; kk < E; kk += 8) {
        #pragma unroll
        for (int k = 0; k < 8; k++) wt[k][tid] = we[(size_t)jl * E + kk + k];
        if (tid < 200) { int i = tid >> 3; int k = tid & 7; tp[k][i] = te[(size_t)(t0 + i) * E + kk + k]; }
        __syncthreads();
        #pragma unroll
        for (int k = 0; k < 8; k++) {
            float w = wt[k][tid];
            #pragma unroll
            for (int i = 0; i < 25; i++) acc[i] += tp[k][i] * w;
        }
        __syncthreads();
    }
    if (j < V) {
        float wwj = ws[OFF_WW + j];
        #pragma unroll
        for (int i = 0; i < 25; i++) {
            float M = tts[i] + wwj - 2.f * acc[i];
            ws[OFF_KTW + (size_t)(t0 + i) * V + j] = expf(-2.f * M);
        }
    }
}

// ---------- K_DT[n][t] = exp(-3*sqdist) ----------
__global__ void k_kdt(const float* __restrict__ de, const float* __restrict__ te, float* ws) {
    int gid = blockIdx.x * 256 + threadIdx.x;
    if (gid >= N * T) return;
    int n = gid / T; int t = gid - n * T;
    const float4* dp  = (const float4*)(de + (size_t)n * E);
    const float4* tpp = (const float4*)(te + (size_t)t * E);
    float s = 0.f;
    #pragma unroll 10
    for (int i = 0; i < E / 4; i++) { float4 a = dp[i], b = tpp[i]; s += a.x*b.x + a.y*b.y + a.z*b.z + a.w*b.w; }
    float M = ws[OFF_DD + n] + ws[OFF_TT + t] - 2.f * s;
    ws[OFF_KDT + gid] = expf(-3.f * M);
}

// ---------- persistent sinkhorn: 100 iterations, 1 grid-reduction barrier each ----------
__global__ void k_persist(const float* __restrict__ bow, const float* __restrict__ wwgt,
                          const float* __restrict__ twgt, float* ws) {
    __shared__ float Kl[JPB * SL];   // 50.5 KB  K_TW slice [j][t], stride 101
    __shared__ float Kd[9 * T];      // 3.6 KB   K_DT slice [d][t]
    __shared__ float u_tw[T];
    __shared__ float v_dt[T];
    __shared__ float b_dt[T];
    __shared__ float u_dt[9];
    __shared__ float v_tw[JPB];
    __shared__ float b_tw[JPB];
    __shared__ float red[256];
    __shared__ int sh_ready;

    int tid = threadIdx.x, b = blockIdx.x;
    int j0 = b * JPB;
    int nd = (b < 128) ? 9 : 8;
    int d0 = b * 8 + (b < 128 ? b : 128);
    float* acc_tw = ws + OFF_ACCTW;
    float* acc_dt = ws + OFF_ACCDT;
    int* cnt = (int*)(ws + OFF_CNT);

    // b_dt = softmax(topic_weights), block-redundant
    float twv = (tid < T) ? twgt[tid] : -INFINITY;
    red[tid] = twv; __syncthreads();
    for (int s = 128; s > 0; s >>= 1) { if (tid < s) red[tid] = fmaxf(red[tid], red[tid + s]); __syncthreads(); }
    float m2 = red[0]; __syncthreads();
    float e2 = (tid < T) ? expf(twv - m2) : 0.f;
    red[tid] = e2; __syncthreads();
    for (int s = 128; s > 0; s >>= 1) { if (tid < s) red[tid] += red[tid + s]; __syncthreads(); }
    if (tid < T) b_dt[tid] = e2 / red[0];
    __syncthreads();

    // combine word-softmax partials -> b_tw slice
    red[tid] = (tid < 118) ? ws[OFF_PM + tid] : -INFINITY; __syncthreads();
    for (int s = 128; s > 0; s >>= 1) { if (tid < s) red[tid] = fmaxf(red[tid], red[tid + s]); __syncthreads(); }
    float mw = red[0]; __syncthreads();
    red[tid] = (tid < 118) ? ws[OFF_PS + tid] * expf(ws[OFF_PM + tid] - mw) : 0.f; __syncthreads();
    for (int s = 128; s > 0; s >>= 1) { if (tid < s) red[tid] += red[tid + s]; __syncthreads(); }
    float Sw = red[0];
    if (tid < JPB) b_tw[tid] = expf(wwgt[j0 + tid] - mw) / Sw;

    // load K slices into LDS
    if (tid < JPB) {
        #pragma unroll 4
        for (int t = 0; t < T; t++)
            Kl[tid * SL + t] = ws[OFF_KTW + (size_t)t * V + j0 + tid];
    }
    if (tid < T) {
        for (int d = 0; d < nd; d++)
            Kd[d * T + tid] = ws[OFF_KDT + (size_t)(d0 + d) * T + tid];
    }
    if (tid < T) u_tw[tid] = 1.f / T;
    if (tid < 9) u_dt[tid] = 1.f / N;
    __syncthreads();

    float bowacc = 0.f;
    int bq = 0;                                   // bow quantum cursor (uniform)
    int jloc = (tid < JPB) ? tid : tid - JPB;     // used only when tid<250
    int rowoff = (tid < JPB) ? 0 : 1;

    for (int k = 0; k < NITER; k++) {
        // TW v-pass: v_{k+1} = b / (K^T u_k)
        if (tid < JPB) {
            float s = 0.f;
            #pragma unroll 4
            for (int t = 0; t < T; t++) s += Kl[tid * SL + t] * u_tw[t];
            v_tw[tid] = b_tw[tid] / (s + EPS_OT);
        }
        __syncthreads();
        // partial K v (TW, over my columns) and partial K^T u (DT, over my docs)
        if (tid < T) {
            float p = 0.f;
            #pragma unroll 5
            for (int j = 0; j < JPB; j++) p += Kl[j * SL + tid] * v_tw[j];
            atomicAdd(&acc_tw[k * T + tid], p);
            float q = 0.f;
            for (int d = 0; d < nd; d++) q += Kd[d * T + tid] * u_dt[d];
            atomicAdd(&acc_dt[k * T + tid], q);
        }
        __syncthreads();   // drains all this block's atomics (vmcnt(0) before s_barrier)
        if (tid == 0) __hip_atomic_fetch_add(&cnt[k], 1, __ATOMIC_RELEASE, __HIP_MEMORY_SCOPE_AGENT);
        // spin on counter; stream bow slice while waiting
        for (;;) {
            if (tid == 0) sh_ready = (__hip_atomic_load(&cnt[k], __ATOMIC_ACQUIRE, __HIP_MEMORY_SCOPE_AGENT) >= NB);
            __syncthreads();
            int done = sh_ready;
            __syncthreads();
            if (done) break;
            if (bq < 256) {
                if (tid < 250) {
                    int base = bq * 8 + rowoff;
                    bowacc += bow[(size_t)(base + 0) * V + j0 + jloc];
                    bowacc += bow[(size_t)(base + 2) * V + j0 + jloc];
                    bowacc += bow[(size_t)(base + 4) * V + j0 + jloc];
                    bowacc += bow[(size_t)(base + 6) * V + j0 + jloc];
                }
                bq++;
            } else {
                __builtin_amdgcn_s_sleep(2);
            }
        }
        // read back reductions; update u_tw, v_dt, u_dt
        if (tid < T) {
            float at = __hip_atomic_load(&acc_tw[k * T + tid], __ATOMIC_RELAXED, __HIP_MEMORY_SCOPE_AGENT);
            u_tw[tid] = (1.f / T) / (at + EPS_OT);
            float ad = __hip_atomic_load(&acc_dt[k * T + tid], __ATOMIC_RELAXED, __HIP_MEMORY_SCOPE_AGENT);
            v_dt[tid] = b_dt[tid] / (ad + EPS_OT);
        }
        __syncthreads();
        if (tid < nd) {
            float s = 0.f;
            #pragma unroll 4
            for (int t = 0; t < T; t++) s += Kd[tid * T + t] * v_dt[t];
            u_dt[tid] = (1.f / N) / (s + EPS_OT);
        }
        __syncthreads();
    }

    // drain remaining bow quanta
    while (bq < 256) {
        if (tid < 250) {
            int base = bq * 8 + rowoff;
            bowacc += bow[(size_t)(base + 0) * V + j0 + jloc];
            bowacc += bow[(size_t)(base + 2) * V + j0 + jloc];
            bowacc += bow[(size_t)(base + 4) * V + j0 + jloc];
            bowacc += bow[(size_t)(base + 6) * V + j0 + jloc];
        }
        bq++;
    }
    red[tid] = bowacc; __syncthreads();
    for (int s = 128; s > 0; s >>= 1) { if (tid < s) red[tid] += red[tid + s]; __syncthreads(); }
    if (tid == 0) atomicAdd((double*)(ws + OFF_DBL) + 3, (double)red[0]);

    // publish finals for slow-path DSR
    if (tid < JPB) ws[OFF_VTW + j0 + tid] = v_tw[tid];
    if (tid < nd) ws[OFF_UDT + d0 + tid] = u_dt[tid];
    if (b == 0 && tid < T) { ws[OFF_UTW + tid] = u_tw[tid]; ws[OFF_VDT + tid] = v_dt[tid]; }

    // loss_TW partial: sum u*K*v*M over my columns, M = -ln(K)/2
    float lt = 0.f;
    if (tid < JPB) {
        float vj = v_tw[tid];
        for (int t = 0; t < T; t++) {
            float kv = Kl[tid * SL + t];
            if (kv > 0.f) lt += u_tw[t] * kv * vj * (-0.5f * logf(kv));
        }
    }
    __syncthreads();
    red[tid] = lt; __syncthreads();
    for (int s = 128; s > 0; s >>= 1) { if (tid < s) red[tid] += red[tid + s]; __syncthreads(); }
    if (tid == 0) atomicAdd((double*)(ws + OFF_DBL) + 2, (double)red[0]);

    // loss_DT partial + theta-nonzero flag, M = -ln(K)/3
    float ld = 0.f; int nz = 0;
    if (tid < T) {
        for (int d = 0; d < nd; d++) {
            float kv = Kd[d * T + tid];
            if (kv > 0.f) ld += u_dt[d] * kv * v_dt[tid] * (-(1.f / 3.f) * logf(kv));
            float th = (float)N * u_dt[d] * kv * v_dt[tid];
            if (th != 0.f) nz = 1;
        }
    }
    __syncthreads();
    red[tid] = ld; __syncthreads();
    for (int s = 128; s > 0; s >>= 1) { if (tid < s) red[tid] += red[tid + s]; __syncthreads(); }
    if (tid == 0) atomicAdd((double*)(ws + OFF_DBL) + 1, (double)red[0]);
    if (nz) atomicOr((int*)(ws + OFF_FLAG), 1);
}

// ---------- DSR slow path only (theta != 0 somewhere) ----------
__global__ void k_dsr(const float* __restrict__ bow, float* ws) {
    if (*(volatile int*)(ws + OFF_FLAG) == 0) return;   // fast path handled in k_persist
    __shared__ float th[32 * T];
    __shared__ float u2[T];
    __shared__ float vd[T];
    __shared__ float red[256];
    __shared__ int flag;
    int tid = threadIdx.x;
    int j0 = blockIdx.x * 256;
    int d0 = blockIdx.y * 32;
    if (tid < T) { vd[tid] = ws[OFF_VDT + tid]; u2[tid] = ws[OFF_UTW + tid]; }
    if (tid == 0) flag = 0;
    __syncthreads();
    bool nz = false;
    for (int idx = tid; idx < 32 * T; idx += 256) {
        int dl = idx / T; int t = idx - dl * T;
        float thv = (float)N * ws[OFF_UDT + d0 + dl] * ws[OFF_KDT + (size_t)(d0 + dl) * T + t] * vd[t];
        th[idx] = thv;
        nz |= (thv != 0.f);
    }
    if (nz) flag = 1;
    __syncthreads();
    int j = j0 + tid;
    float part = 0.f;
    if (flag) {
        float acc[32];
        #pragma unroll
        for (int d = 0; d < 32; d++) acc[d] = 0.f;
        if (j < V) {
            float vj = ws[OFF_VTW + j];
            for (int t = 0; t < T; t++) {
                float kv = ws[OFF_KTW + (size_t)t * V + j];
                float beta = (float)T * u2[t] * kv * vj;
                #pragma unroll
                for (int d = 0; d < 32; d++) acc[d] += th[d * T + t] * beta;
            }
            for (int d = 0; d < 32; d++)
                part += bow[(size_t)(d0 + d) * V + j] * logf(acc[d] + EPS_LOG);
        }
    } else {
        if (j < V) {
            float sb = 0.f;
            #pragma unroll 8
            for (int d = 0; d < 32; d++) sb += bow[(size_t)(d0 + d) * V + j];
            part = sb * logf(EPS_LOG);
        }
    }
    red[tid] = part; __syncthreads();
    for (int s = 128; s > 0; s >>= 1) { if (tid < s) red[tid] += red[tid + s]; __syncthreads(); }
    if (tid == 0) atomicAdd((double*)(ws + OFF_DBL) + 0, (double)red[0]);
}

// ---------- combine ----------
__global__ void k_finish(float* ws, float* out) {
    if (threadIdx.x == 0 && blockIdx.x == 0) {
        double* dbl = (double*)(ws + OFF_DBL);
        int flag = *(int*)(ws + OFF_FLAG);
        double dsr_sum = flag ? dbl[0] : dbl[3] * (double)logf(EPS_LOG);
        double ldsr = -dsr_sum / (double)N;
        double letp = dbl[1] + dbl[2];
        out[0] = (float)(ldsr + letp);
        out[1] = (float)ldsr;
        out[2] = (float)letp;
    }
}

extern "C" void kernel_launch(void* const* d_in, const int* in_sizes, int n_in,
                              void* d_out, int out_size, void* d_ws, size_t ws_size,
                              hipStream_t stream) {
    const float* bow  = (const float*)d_in[0];
    const float* de   = (const float*)d_in[1];
    const float* we   = (const float*)d_in[2];
    const float* te   = (const float*)d_in[3];
    const float* wwgt = (const float*)d_in[4];
    const float* twgt = (const float*)d_in[5];
    float* out = (float*)d_out;
    float* ws  = (float*)d_ws;

    k_pre<<<128, 256, 0, stream>>>(we, de, te, wwgt, ws);
    k_ktw<<<dim3(118, 4), 256, 0, stream>>>(we, te, ws);
    k_kdt<<<800, 256, 0, stream>>>(de, te, ws);
    void* args[] = { (void*)&bow, (void*)&wwgt, (void*)&twgt, (void*)&ws };
    hipLaunchCooperativeKernel((void*)k_persist, dim3(NB), dim3(256), args, 0, stream);
    k_dsr<<<dim3(118, 64), 256, 0, stream>>>(bow, ws);
    k_finish<<<1, 64, 0, stream>>>(ws, out);
}

// Round 3
// 2139.150 us; speedup vs baseline: 1.0767x; 1.0767x over previous
//
#include <hip/hip_runtime.h>
#include <math.h>

#define V 30000
#define E 200
#define T 100
#define N 2048
#define NITER 100
#define NBS 120          // sinkhorn blocks (barrier participants)
#define NBB 392          // bow-streaming blocks
#define NBTOT 512        // total grid (<= worst-case co-residency 2/CU*256)
#define JPB 250          // words per sinkhorn block (120*250 = 30000)
#define PSTRIDE 104      // partial row stride (floats)
#define EPS_OT 1e-16f
#define EPS_LOG 1e-12f

// ws float offsets
#define OFF_KTW   0            // ushort[T*V] bf16 = 1,500,000 floats
#define OFF_KDT   1500000      // float[N*T]
#define OFF_WW    1704800      // V
#define OFF_DD    1734800      // N
#define OFF_TT    1736848      // 128
#define OFF_PM    1736976      // 128  word-softmax per-block max
#define OFF_PS    1737104      // 128  word-softmax per-block sum
#define OFF_ACCDT 1737232      // NITER*T (DT slow path only)
#define OFF_PART  1747232      // 2*NBS*PSTRIDE = 24,960 TW partials
#define OFF_VTW   1772192      // V
#define OFF_UDT   1802192      // N
#define OFF_UTW   1804240      // 128
#define OFF_VDT   1804368      // 128
#define OFF_DBL   1804496      // 16 floats = 8 doubles: [0]=dsr_slow [1]=l_dt [2]=l_tw [3]=bow_sum
#define OFF_CNT   1804512      // 128 ints (iteration counters)
#define OFF_FLAG  1804640      // int: theta nonzero
#define OFF_KDTNZ 1804641      // int: any K_DT nonzero

__device__ __forceinline__ unsigned short f2bf(float f) {
    unsigned int u = __float_as_uint(f);
    return (unsigned short)((u + 0x7fffu + ((u >> 16) & 1u)) >> 16);
}
__device__ __forceinline__ float bf2f(unsigned short h) {
    return __uint_as_float(((unsigned int)h) << 16);
}

__device__ __forceinline__ float brsum(float x, float* red8) {
    int tid = threadIdx.x;
    for (int o = 32; o; o >>= 1) x += __shfl_down(x, o, 64);
    __syncthreads();
    if ((tid & 63) == 0) red8[tid >> 6] = x;
    __syncthreads();
    return (red8[0] + red8[1]) + (red8[2] + red8[3]);
}
__device__ __forceinline__ float brmax(float x, float* red8) {
    int tid = threadIdx.x;
    for (int o = 32; o; o >>= 1) x = fmaxf(x, __shfl_down(x, o, 64));
    __syncthreads();
    if ((tid & 63) == 0) red8[tid >> 6] = x;
    __syncthreads();
    return fmaxf(fmaxf(red8[0], red8[1]), fmaxf(red8[2], red8[3]));
}

// ---------- zeroing + row norms + word-softmax partials ----------
__global__ void k_pre(const float* __restrict__ we, const float* __restrict__ de,
                      const float* __restrict__ te, const float* __restrict__ wwgt,
                      float* ws) {
    __shared__ float red[256];
    int tid = threadIdx.x, b = blockIdx.x;
    int gid = b * 256 + tid;
    if (gid < NITER * T) ws[OFF_ACCDT + gid] = 0.f;
    if (gid < 16) ws[OFF_DBL + gid] = 0.f;
    if (gid < 128) ((int*)ws)[OFF_CNT + gid] = 0;
    if (gid < 2) ((int*)ws)[OFF_FLAG + gid] = 0;
    {   // squared row norms
        int r = gid;
        const float* src = nullptr; float* dst = nullptr; int row = 0;
        if (r < V)              { src = we; dst = ws + OFF_WW; row = r; }
        else if (r < V + N)     { src = de; dst = ws + OFF_DD; row = r - V; }
        else if (r < V + N + T) { src = te; dst = ws + OFF_TT; row = r - V - N; }
        if (src) {
            const float4* p = (const float4*)(src + (size_t)row * E);
            float s = 0.f;
            #pragma unroll 10
            for (int i = 0; i < E / 4; i++) { float4 v = p[i]; s += v.x*v.x + v.y*v.y + v.z*v.z + v.w*v.w; }
            dst[row] = s;
        }
    }
    if (b < 118) {  // word-softmax partials, merged per-block in k_persist
        int j = gid;
        float w = (j < V) ? wwgt[j] : -INFINITY;
        red[tid] = w; __syncthreads();
        for (int s = 128; s > 0; s >>= 1) { if (tid < s) red[tid] = fmaxf(red[tid], red[tid + s]); __syncthreads(); }
        float m = red[0]; __syncthreads();
        float e = (j < V) ? expf(w - m) : 0.f;
        red[tid] = e; __syncthreads();
        for (int s = 128; s > 0; s >>= 1) { if (tid < s) red[tid] += red[tid + s]; __syncthreads(); }
        if (tid == 0) { ws[OFF_PM + b] = m; ws[OFF_PS + b] = red[0]; }
    }
}

// ---------- K_TW[t][j] = bf16(exp(-2*sqdist)) ----------
__global__ void k_ktw(const float* __restrict__ we, const float* __restrict__ te, float* ws) {
    __shared__ float wt[8][256];
    __shared__ float tp[8][25];
    __shared__ float tts[25];
    int tid = threadIdx.x;
    int j0 = blockIdx.x * 256;
    int t0 = blockIdx.y * 25;
    int j = j0 + tid;
    int jl = (j < V) ? j : V - 1;
    float acc[25];
    #pragma unroll
    for (int i = 0; i < 25; i++) acc[i] = 0.f;
    if (tid < 25) tts[tid] = ws[OFF_TT + t0 + tid];
    for (int kk = 0; kk < E; kk += 8) {
        #pragma unroll
        for (int k = 0; k < 8; k++) wt[k][tid] = we[(size_t)jl * E + kk + k];
        if (tid < 200) { int i = tid >> 3; int k = tid & 7; tp[k][i] = te[(size_t)(t0 + i) * E + kk + k]; }
        __syncthreads();
        #pragma unroll
        for (int k = 0; k < 8; k++) {
            float w = wt[k][tid];
            #pragma unroll
            for (int i = 0; i < 25; i++) acc[i] += tp[k][i] * w;
        }
        __syncthreads();
    }
    if (j < V) {
        float wwj = ws[OFF_WW + j];
        unsigned short* kg = (unsigned short*)(ws + OFF_KTW);
        #pragma unroll
        for (int i = 0; i < 25; i++) {
            float M = tts[i] + wwj - 2.f * acc[i];
            kg[(size_t)(t0 + i) * V + j] = f2bf(expf(-2.f * M));
        }
    }
}

// ---------- K_DT[n][t] = exp(-3*sqdist), fp32, + any-nonzero flag ----------
__global__ void k_kdt(const float* __restrict__ de, const float* __restrict__ te, float* ws) {
    int gid = blockIdx.x * 256 + threadIdx.x;
    if (gid >= N * T) return;
    int n = gid / T; int t = gid - n * T;
    const float4* dp  = (const float4*)(de + (size_t)n * E);
    const float4* tpp = (const float4*)(te + (size_t)t * E);
    float s = 0.f;
    #pragma unroll 10
    for (int i = 0; i < E / 4; i++) { float4 a = dp[i], b = tpp[i]; s += a.x*b.x + a.y*b.y + a.z*b.z + a.w*b.w; }
    float M = ws[OFF_DD + n] + ws[OFF_TT + t] - 2.f * s;
    float kv = expf(-3.f * M);
    ws[OFF_KDT + gid] = kv;
    unsigned long long m = __ballot(kv != 0.f);
    if (m && (threadIdx.x & 63) == 0) atomicOr(((int*)ws) + OFF_KDTNZ, 1);
}

// ---------- persistent: 120 sinkhorn blocks + 392 bow-streaming blocks ----------
__global__ void __launch_bounds__(256, 3)
k_persist(const float* __restrict__ bow, const float* __restrict__ wwgt,
          const float* __restrict__ twgt, float* ws) {
    __shared__ unsigned short Kl[T * JPB];   // 50,000 B, [t][j] bf16
    __shared__ __align__(16) float v_tw[JPB];
    __shared__ __align__(16) float u_tw[T];
    __shared__ float b_dt[T];
    __shared__ float v_dt[T];
    __shared__ float u_dt[18];
    __shared__ float red8[8];
    int tid = threadIdx.x, b = blockIdx.x;

    if (b >= NBS) {  // ---- bow role: total-sum of train_bow ----
        const float4* b4 = (const float4*)bow;
        float s = 0.f;
        size_t total4 = (size_t)N * V / 4;
        for (size_t i = (size_t)(b - NBS) * 256 + tid; i < total4; i += (size_t)NBB * 256) {
            float4 x = b4[i]; s += (x.x + x.y) + (x.z + x.w);
        }
        float bs = brsum(s, red8);
        if (tid == 0) atomicAdd((double*)(ws + OFF_DBL) + 3, (double)bs);
        return;
    }

    // ---- sinkhorn role ----
    int j0 = b * JPB;
    int jl = tid;                                  // word lane, valid < JPB
    int kdtnz = *(((volatile int*)ws) + OFF_KDTNZ);

    // b_dt = softmax(topic_weights), block-redundant
    float x = (tid < T) ? twgt[tid] : -INFINITY;
    float mt = brmax(x, red8);
    float e = (tid < T) ? expf(x - mt) : 0.f;
    float se = brsum(e, red8);
    if (tid < T) b_dt[tid] = e / se;

    // merge word-softmax partials -> per-thread b_tw (register)
    float pm = (tid < 118) ? ws[OFF_PM + tid] : -INFINITY;
    float mw = brmax(pm, red8);
    float psc = (tid < 118) ? ws[OFF_PS + tid] * expf(ws[OFF_PM + tid] - mw) : 0.f;
    float Sw = brsum(psc, red8);
    float b_tw = (jl < JPB) ? expf(wwgt[j0 + jl] - mw) / Sw : 0.f;

    // load K slice: LDS [t][j] + per-thread packed register column
    const unsigned short* kg = (const unsigned short*)(ws + OFF_KTW);
    unsigned int col[50];
    #pragma unroll 4
    for (int t = 0; t < T; t++) {
        unsigned short kv = (jl < JPB) ? kg[(size_t)t * V + j0 + jl] : 0;
        if (jl < JPB) Kl[t * JPB + jl] = kv;
        if (t & 1) col[t >> 1] |= ((unsigned int)kv) << 16; else col[t >> 1] = kv;
    }
    if (tid < T) u_tw[tid] = 1.f / T;
    if (tid < 18) u_dt[tid] = 1.f / N;
    int nd = 17 + (b < 8 ? 1 : 0);
    int d0 = b * 17 + (b < 8 ? b : 8);
    __syncthreads();

    int* cnt = ((int*)ws) + OFF_CNT;
    float* acc_dt = ws + OFF_ACCDT;

    for (int k = 0; k < NITER; k++) {
        int buf = k & 1;
        // v-pass (registers + u broadcast)
        float vj = 0.f;
        if (jl < JPB) {
            float s = 0.f;
            #pragma unroll
            for (int t2 = 0; t2 < 50; t2++) {
                unsigned int c = col[t2];
                float2 uu = *(const float2*)&u_tw[2 * t2];
                s += __uint_as_float(c << 16) * uu.x;
                s += __uint_as_float(c & 0xffff0000u) * uu.y;
            }
            vj = b_tw / (s + EPS_OT);
            v_tw[jl] = vj;
        }
        __syncthreads();
        // partial K.v over my columns -> disjoint per-block slot (no RMW)
        if (tid < T) {
            const unsigned int* Kr = (const unsigned int*)&Kl[tid * JPB];
            float s = 0.f;
            #pragma unroll 5
            for (int jj = 0; jj < JPB / 2; jj++) {
                unsigned int c = Kr[jj];
                float2 vv = *(const float2*)&v_tw[2 * jj];
                s += __uint_as_float(c << 16) * vv.x;
                s += __uint_as_float(c & 0xffff0000u) * vv.y;
            }
            __hip_atomic_store(ws + OFF_PART + (size_t)(buf * NBS + b) * PSTRIDE + tid, s,
                               __ATOMIC_RELEASE, __HIP_MEMORY_SCOPE_AGENT);
            if (kdtnz) {  // DT slow path (gated, correctness-only)
                float q = 0.f;
                for (int d = 0; d < nd; d++) q += ws[OFF_KDT + (size_t)(d0 + d) * T + tid] * u_dt[d];
                atomicAdd(&acc_dt[k * T + tid], q);
            }
        }
        __syncthreads();
        if (tid == 0) {
            __hip_atomic_fetch_add(cnt + k, 1, __ATOMIC_RELEASE, __HIP_MEMORY_SCOPE_AGENT);
            int c;
            do {
                __builtin_amdgcn_s_sleep(1);
                c = __hip_atomic_load(cnt + k, __ATOMIC_ACQUIRE, __HIP_MEMORY_SCOPE_AGENT);
            } while (c < NBS);
        }
        __syncthreads();
        // readback partials -> u_tw (and DT slow path)
        if (tid < T) {
            const float* pp = ws + OFF_PART + (size_t)buf * NBS * PSTRIDE + tid;
            float s = 0.f;
            #pragma unroll 8
            for (int b2 = 0; b2 < NBS; b2++)
                s += __hip_atomic_load(pp + (size_t)b2 * PSTRIDE, __ATOMIC_RELAXED, __HIP_MEMORY_SCOPE_AGENT);
            u_tw[tid] = (1.f / T) / (s + EPS_OT);
            if (kdtnz) {
                float ad = __hip_atomic_load(&acc_dt[k * T + tid], __ATOMIC_RELAXED, __HIP_MEMORY_SCOPE_AGENT);
                v_dt[tid] = b_dt[tid] / (ad + EPS_OT);
            }
        }
        __syncthreads();
        if (kdtnz) {
            if (tid < nd) {
                float s = 0.f;
                for (int t2 = 0; t2 < T; t2++) s += ws[OFF_KDT + (size_t)(d0 + tid) * T + t2] * v_dt[t2];
                u_dt[tid] = (1.f / N) / (s + EPS_OT);
            }
            __syncthreads();
        }
    }

    // loss_TW = sum u*K*v*M, M = -ln(K)/2 (skip K==0: transp elem exactly 0)
    float lt = 0.f;
    if (jl < JPB) {
        float vjf = v_tw[jl];
        #pragma unroll 5
        for (int t2 = 0; t2 < 50; t2++) {
            unsigned int c = col[t2];
            float k0 = __uint_as_float(c << 16);
            float k1 = __uint_as_float(c & 0xffff0000u);
            float2 uu = *(const float2*)&u_tw[2 * t2];
            if (k0 > 0.f) lt += uu.x * k0 * vjf * (-0.5f * logf(k0));
            if (k1 > 0.f) lt += uu.y * k1 * vjf * (-0.5f * logf(k1));
        }
    }
    float ltb = brsum(lt, red8);
    if (tid == 0) atomicAdd((double*)(ws + OFF_DBL) + 2, (double)ltb);

    if (kdtnz) {  // DT loss + publishes for k_dsr slow path
        if (jl < JPB) ws[OFF_VTW + j0 + jl] = v_tw[jl];
        if (b == 0 && tid < T) { ws[OFF_UTW + tid] = u_tw[tid]; ws[OFF_VDT + tid] = v_dt[tid]; }
        if (tid < nd) ws[OFF_UDT + d0 + tid] = u_dt[tid];
        float ld = 0.f; int nzloc = 0;
        if (tid < T) {
            for (int d = 0; d < nd; d++) {
                float kv = ws[OFF_KDT + (size_t)(d0 + d) * T + tid];
                if (kv > 0.f) ld += u_dt[d] * kv * v_dt[tid] * (-(1.f / 3.f) * logf(kv));
                if ((float)N * u_dt[d] * kv * v_dt[tid] != 0.f) nzloc = 1;
            }
        }
        float ldb = brsum(ld, red8);
        if (tid == 0) atomicAdd((double*)(ws + OFF_DBL) + 1, (double)ldb);
        if (nzloc) atomicOr(((int*)ws) + OFF_FLAG, 1);
    }
}

// ---------- DSR slow path only (theta != 0 somewhere) ----------
__global__ void k_dsr(const float* __restrict__ bow, float* ws) {
    if (*(volatile int*)(((int*)ws) + OFF_FLAG) == 0) return;
    __shared__ float th[32 * T];
    __shared__ float u2[T];
    __shared__ float vd[T];
    __shared__ float red[256];
    __shared__ int flag;
    int tid = threadIdx.x;
    int j0 = blockIdx.x * 256;
    int d0 = blockIdx.y * 32;
    if (tid < T) { vd[tid] = ws[OFF_VDT + tid]; u2[tid] = ws[OFF_UTW + tid]; }
    if (tid == 0) flag = 0;
    __syncthreads();
    bool nz = false;
    for (int idx = tid; idx < 32 * T; idx += 256) {
        int dl = idx / T; int t = idx - dl * T;
        float thv = (float)N * ws[OFF_UDT + d0 + dl] * ws[OFF_KDT + (size_t)(d0 + dl) * T + t] * vd[t];
        th[idx] = thv;
        nz |= (thv != 0.f);
    }
    if (nz) flag = 1;
    __syncthreads();
    int j = j0 + tid;
    float part = 0.f;
    const unsigned short* kg = (const unsigned short*)(ws + OFF_KTW);
    if (flag) {
        float acc[32];
        #pragma unroll
        for (int d = 0; d < 32; d++) acc[d] = 0.f;
        if (j < V) {
            float vj = ws[OFF_VTW + j];
            for (int t = 0; t < T; t++) {
                float kv = bf2f(kg[(size_t)t * V + j]);
                float beta = (float)T * u2[t] * kv * vj;
                #pragma unroll
                for (int d = 0; d < 32; d++) acc[d] += th[d * T + t] * beta;
            }
            for (int d = 0; d < 32; d++)
                part += bow[(size_t)(d0 + d) * V + j] * logf(acc[d] + EPS_LOG);
        }
    } else {
        if (j < V) {
            float sb = 0.f;
            #pragma unroll 8
            for (int d = 0; d < 32; d++) sb += bow[(size_t)(d0 + d) * V + j];
            part = sb * logf(EPS_LOG);
        }
    }
    red[tid] = part; __syncthreads();
    for (int s = 128; s > 0; s >>= 1) { if (tid < s) red[tid] += red[tid + s]; __syncthreads(); }
    if (tid == 0) atomicAdd((double*)(ws + OFF_DBL) + 0, (double)red[0]);
}

// ---------- combine ----------
__global__ void k_finish(float* ws, float* out) {
    if (threadIdx.x == 0 && blockIdx.x == 0) {
        double* dbl = (double*)(ws + OFF_DBL);
        int flag = *(((int*)ws) + OFF_FLAG);
        double dsr_sum = flag ? dbl[0] : dbl[3] * (double)logf(EPS_LOG);
        double ldsr = -dsr_sum / (double)N;
        double letp = dbl[1] + dbl[2];
        out[0] = (float)(ldsr + letp);
        out[1] = (float)ldsr;
        out[2] = (float)letp;
    }
}

extern "C" void kernel_launch(void* const* d_in, const int* in_sizes, int n_in,
                              void* d_out, int out_size, void* d_ws, size_t ws_size,
                              hipStream_t stream) {
    const float* bow  = (const float*)d_in[0];
    const float* de   = (const float*)d_in[1];
    const float* we   = (const float*)d_in[2];
    const float* te   = (const float*)d_in[3];
    const float* wwgt = (const float*)d_in[4];
    const float* twgt = (const float*)d_in[5];
    float* out = (float*)d_out;
    float* ws  = (float*)d_ws;

    k_pre<<<128, 256, 0, stream>>>(we, de, te, wwgt, ws);
    k_ktw<<<dim3(118, 4), 256, 0, stream>>>(we, te, ws);
    k_kdt<<<800, 256, 0, stream>>>(de, te, ws);
    void* args[] = { (void*)&bow, (void*)&wwgt, (void*)&twgt, (void*)&ws };
    hipError_t ce = hipLaunchCooperativeKernel((void*)k_persist, dim3(NBTOT), dim3(256),
                                               args, 0, stream);
    if (ce != hipSuccess)   // fallback: low-ID blocks dispatch first; 120 << 256 CUs
        k_persist<<<NBTOT, 256, 0, stream>>>(bow, wwgt, twgt, ws);
    k_dsr<<<dim3(118, 64), 256, 0, stream>>>(bow, ws);
    k_finish<<<1, 64, 0, stream>>>(ws, out);
}